// Round 1
// baseline (133.087 us; speedup 1.0000x reference)
//
#include <hip/hip_runtime.h>
#include <math.h>

#define NB 32
#define NA 3
#define NC 80
#define NH 56
#define NW 56
#define NT 50
#define HW (NH*NW)          // 3136
#define CELLS_PER_B (NA*HW) // 9408
#define CH_PER_A (5+NC)     // 85
#define SILF 0.6f
#define EPSF 1e-7f

__device__ __forceinline__ float sigmoidf_(float v) { return 1.0f / (1.0f + expf(-v)); }

// ---------------------------------------------------------------------------
// Kernel 1: per-target prep. 1600 targets.
//  - scale boxes to grid coords
//  - best anchor (argmax anchor-IoU, first-max-wins)
//  - flat cell index (global, includes batch)
//  - zero the 4 accumulator floats
// ---------------------------------------------------------------------------
__global__ void prep_kernel(const float* __restrict__ tb,
                            float4* __restrict__ gbox,
                            int* __restrict__ gflat,
                            float* __restrict__ accum) {
    int tid = blockIdx.x * blockDim.x + threadIdx.x;
    if (tid < 4) accum[tid] = 0.0f;
    if (tid >= NB * NT) return;

    const float* p = tb + tid * 4;
    float bw = p[2];
    bool valid = bw > 0.0f;
    float gx = p[0] * (float)NW;
    float gy = p[1] * (float)NH;
    float gw = bw * (float)NW;
    float gh = p[3] * (float)NH;

    if (!valid) {
        gbox[tid] = make_float4(1e9f, 1e9f, 0.0f, 0.0f);  // never intersects, no NaN
        gflat[tid] = -1;
        return;
    }
    gbox[tid] = make_float4(gx, gy, gw, gh);

    const float aw[3] = {1.28967f, 2.12714f, 3.27212f};
    const float ah[3] = {4.15014f, 5.09344f, 5.87423f};
    int bn = 0;
    float best = -1.0f;
    #pragma unroll
    for (int k = 0; k < 3; ++k) {
        float inter = fminf(aw[k], gw) * fminf(ah[k], gh);
        float uni = aw[k] * ah[k] + gw * gh - inter;
        float r = inter / uni;
        if (r > best) { best = r; bn = k; }
    }
    int gi = (int)gx; gi = gi < 0 ? 0 : (gi > NW - 1 ? NW - 1 : gi);
    int gj = (int)gy; gj = gj < 0 ? 0 : (gj > NH - 1 ? NH - 1 : gj);
    int b = tid / NT;
    gflat[tid] = ((b * NA + bn) * NH + gj) * NW + gi;  // == b*9408 + bn*3136 + gj*56 + gi
}

// ---------------------------------------------------------------------------
// Kernel 2: main loss. grid (ceil(9408/256), 32), block 256.
// ---------------------------------------------------------------------------
__global__ __launch_bounds__(256) void main_kernel(const float* __restrict__ out,
                                                   const float4* __restrict__ gbox,
                                                   const int* __restrict__ gflat,
                                                   const float* __restrict__ tcls,
                                                   const float* __restrict__ cwt,
                                                   float* __restrict__ accum) {
    __shared__ float sx1[NT], sx2[NT], sy1[NT], sy2[NT], sw_[NT], sh_[NT], sar[NT];
    __shared__ int sfl[NT];

    const int b = blockIdx.y;
    const int tid = threadIdx.x;

    if (tid < NT) {
        float4 g = gbox[b * NT + tid];
        sx1[tid] = g.x - 0.5f * g.z;
        sx2[tid] = g.x + 0.5f * g.z;
        sy1[tid] = g.y - 0.5f * g.w;
        sy2[tid] = g.y + 0.5f * g.w;
        sw_[tid] = g.z;
        sh_[tid] = g.w;
        sar[tid] = g.z * g.w;
        sfl[tid] = gflat[b * NT + tid];
    }
    __syncthreads();

    const int lc = blockIdx.x * blockDim.x + tid;
    float lmain = 0.0f, lcls = 0.0f, lnsel = 0.0f;

    if (lc < CELLS_PER_B) {
        const int a = lc / HW;
        const int rem = lc - a * HW;
        const int j = rem / NW;
        const int i = rem - j * NW;

        const float aw[3] = {1.28967f, 2.12714f, 3.27212f};
        const float ah[3] = {4.15014f, 5.09344f, 5.87423f};

        const float* base = out + (size_t)b * (NA * CH_PER_A * HW) + (size_t)(a * CH_PER_A) * HW + rem;
        float o0 = base[0];
        float o1 = base[HW];
        float o2 = base[2 * HW];
        float o3 = base[3 * HW];
        float o4 = base[4 * HW];

        float x = sigmoidf_(o0);
        float y = sigmoidf_(o1);
        float conf = sigmoidf_(o4);
        float pw = expf(o2) * aw[a];
        float ph = expf(o3) * ah[a];
        float px = x + (float)i;
        float py = y + (float)j;
        float px1 = px - 0.5f * pw, px2 = px + 0.5f * pw;
        float py1 = py - 0.5f * ph, py2 = py + 0.5f * ph;
        float parea = pw * ph;

        const int cell = b * CELLS_PER_B + lc;

        bool sil = false;
        int tsel = -1;
        for (int t = 0; t < NT; ++t) {
            float mx = fminf(sx1[t], px1);
            float Mx = fmaxf(sx2[t], px2);
            float my = fminf(sy1[t], py1);
            float My = fmaxf(sy2[t], py2);
            float cw = sw_[t] + pw - (Mx - mx);
            float chh = sh_[t] + ph - (My - my);
            float inter = (cw <= 0.0f || chh <= 0.0f) ? 0.0f : cw * chh;
            float uni = sar[t] + parea - inter;
            sil = sil || (inter > SILF * uni);        // iou > 0.6  (no division)
            if (sfl[t] == cell) tsel = t;             // last (max t) wins, matches .at[].set
        }

        if (tsel >= 0) {
            // ---- object cell ----
            float4 g = gbox[b * NT + tsel];
            float tx = g.x - (float)i;
            float ty = g.y - (float)j;
            float tw = logf(g.z / aw[a]);
            float th = logf(g.w / ah[a]);
            lmain += 0.5f * ((x - tx) * (x - tx) + (y - ty) * (y - ty) +
                             (o2 - tw) * (o2 - tw) + (o3 - th) * (o3 - th));
            // exact IoU for tconf
            float gx1 = g.x - 0.5f * g.z, gx2 = g.x + 0.5f * g.z;
            float gy1 = g.y - 0.5f * g.w, gy2 = g.y + 0.5f * g.w;
            float mx = fminf(gx1, px1), Mx = fmaxf(gx2, px2);
            float my = fminf(gy1, py1), My = fmaxf(gy2, py2);
            float cw = g.z + pw - (Mx - mx);
            float chh = g.w + ph - (My - my);
            float inter = (cw <= 0.0f || chh <= 0.0f) ? 0.0f : cw * chh;
            float uni = g.z * g.w + parea - inter;
            float tconf = inter / uni;
            lmain += 2.5f * (conf - tconf) * (conf - tconf);   // 0.5 * OBJECT_SCALE
            lnsel = 1.0f;

            // focal class loss, only at object cells
            const float* cb = base + 5 * HW;
            const float* tc = tcls + (size_t)(b * NT + tsel) * NC;
            for (int c = 0; c < NC; ++c) {
                float p = sigmoidf_(cb[(size_t)c * HW]);
                float w = cwt[c];
                float l1 = sqrtf(1.0f - p + EPSF) * logf(p + EPSF) * expf(w);
                float l0 = sqrtf(p + EPSF) * logf(1.0f - p + EPSF) * expf(1.0f - w);
                float t = tc[c];
                lcls += t * l1 + (1.0f - t) * l0;
            }
        } else {
            // non-object: tconf = 0, conf_mask = sil ? 0 : 1
            lmain += sil ? 0.0f : 0.5f * conf * conf;
        }
    }

    // block reduction (wave64 shuffle, then LDS across 4 waves)
    for (int off = 32; off > 0; off >>= 1) {
        lmain += __shfl_down(lmain, off, 64);
        lcls  += __shfl_down(lcls, off, 64);
        lnsel += __shfl_down(lnsel, off, 64);
    }
    __shared__ float red[3][4];
    int wave = tid >> 6;
    if ((tid & 63) == 0) { red[0][wave] = lmain; red[1][wave] = lcls; red[2][wave] = lnsel; }
    __syncthreads();
    if (tid == 0) {
        float m = red[0][0] + red[0][1] + red[0][2] + red[0][3];
        float c = red[1][0] + red[1][1] + red[1][2] + red[1][3];
        float n = red[2][0] + red[2][1] + red[2][2] + red[2][3];
        atomicAdd(&accum[0], m);
        atomicAdd(&accum[1], c);
        atomicAdd(&accum[2], n);
    }
}

// ---------------------------------------------------------------------------
// Kernel 3: finalize.
// ---------------------------------------------------------------------------
__global__ void finalize_kernel(const float* __restrict__ accum, float* __restrict__ outp) {
    float nsel = fmaxf(accum[2], 1.0f);
    outp[0] = accum[0] - accum[1] / nsel;   // CLASS_SCALE=1, loss_cls = -sum/nsel
}

extern "C" void kernel_launch(void* const* d_in, const int* in_sizes, int n_in,
                              void* d_out, int out_size, void* d_ws, size_t ws_size,
                              hipStream_t stream) {
    const float* output = (const float*)d_in[0];
    const float* tb     = (const float*)d_in[1];
    const float* tcls   = (const float*)d_in[2];
    const float* cwt    = (const float*)d_in[3];

    float4* gbox = (float4*)d_ws;                           // 1600 * 16B = 25600
    int*    gflat = (int*)((char*)d_ws + 25600);            // 1600 * 4B  =  6400
    float*  accum = (float*)((char*)d_ws + 32000);          // 16B

    prep_kernel<<<dim3(7), 256, 0, stream>>>(tb, gbox, gflat, accum);
    main_kernel<<<dim3((CELLS_PER_B + 255) / 256, NB), 256, 0, stream>>>(
        output, gbox, gflat, tcls, cwt, accum);
    finalize_kernel<<<1, 1, 0, stream>>>(accum, (float*)d_out);
}

// Round 2
// 35.764 us; speedup vs baseline: 3.7213x; 3.7213x over previous
//
#include <hip/hip_runtime.h>
#include <math.h>

#define NB 32
#define NA 3
#define NC 80
#define NH 56
#define NW 56
#define NT 50
#define HW (NH*NW)          // 3136
#define CELLS_PER_B (NA*HW) // 9408
#define CH_PER_A (5+NC)     // 85
#define EPSF 1e-7f
#define NBLK_X ((CELLS_PER_B + 255) / 256)   // 37
#define NBLK_DENSE (NBLK_X * NB)             // 1184
#define MAXOBJ (NB*NT)                       // 1600

// workspace layout (16B aligned)
#define WS_COUNTER   0
#define WS_TP1       16
#define WS_TP2       (WS_TP1 + MAXOBJ*16)      // 25616
#define WS_OBJLIST   (WS_TP2 + MAXOBJ*16)      // 51216
#define WS_PART      (WS_OBJLIST + MAXOBJ*8)   // 64016
#define WS_CLSPART   (WS_PART + NBLK_DENSE*4)  // 68752

__device__ __forceinline__ float fsig(float v) { return 1.0f / (1.0f + __expf(-v)); }

// ---------------------------------------------------------------------------
// Kernel 1: per-target prep (1600 targets) + zero counter.
// pack1 = {x1, x2, y1, y2}; pack2 = {w, h, 0.6*area, flat_local(bits)}
// ---------------------------------------------------------------------------
__global__ void prep_kernel(const float* __restrict__ tb,
                            float4* __restrict__ tp1,
                            float4* __restrict__ tp2,
                            int* __restrict__ counter) {
    int tid = blockIdx.x * blockDim.x + threadIdx.x;
    if (tid == 0) counter[0] = 0;
    if (tid >= NB * NT) return;

    const float* p = tb + tid * 4;
    float bw = p[2];
    float gx = p[0] * (float)NW;
    float gy = p[1] * (float)NH;
    float gw = bw * (float)NW;
    float gh = p[3] * (float)NH;

    if (!(bw > 0.0f)) {
        tp1[tid] = make_float4(1e9f, 1e9f, 1e9f, 1e9f);
        tp2[tid] = make_float4(0.0f, 0.0f, 0.0f, __int_as_float(-1));
        return;
    }
    tp1[tid] = make_float4(gx - 0.5f * gw, gx + 0.5f * gw,
                           gy - 0.5f * gh, gy + 0.5f * gh);

    const float aw[3] = {1.28967f, 2.12714f, 3.27212f};
    const float ah[3] = {4.15014f, 5.09344f, 5.87423f};
    int bn = 0;
    float best = -1.0f;
    #pragma unroll
    for (int k = 0; k < 3; ++k) {
        float inter = fminf(aw[k], gw) * fminf(ah[k], gh);
        float uni = aw[k] * ah[k] + gw * gh - inter;
        float r = inter / uni;
        if (r > best) { best = r; bn = k; }
    }
    int gi = (int)gx; gi = gi < 0 ? 0 : (gi > NW - 1 ? NW - 1 : gi);
    int gj = (int)gy; gj = gj < 0 ? 0 : (gj > NH - 1 ? NH - 1 : gj);
    int flat_local = (bn * NH + gj) * NW + gi;   // batch-relative
    tp2[tid] = make_float4(gw, gh, 0.6f * gw * gh, __int_as_float(flat_local));
}

// ---------------------------------------------------------------------------
// Kernel 2: dense pass. grid (37, 32), block 256.
//  - silence test (max_iou>0.6) via branchless IoU, no division
//  - coord + conf losses; object cells appended to compact list
//  - per-block partial sum (no float atomics)
// ---------------------------------------------------------------------------
__global__ __launch_bounds__(256) void main_kernel(const float* __restrict__ out,
                                                   const float4* __restrict__ tp1,
                                                   const float4* __restrict__ tp2,
                                                   float* __restrict__ part,
                                                   int2* __restrict__ objlist,
                                                   int* __restrict__ counter) {
    __shared__ float4 sp1[NT], sp2[NT];
    const int b = blockIdx.y;
    const int tid = threadIdx.x;

    if (tid < NT) {
        sp1[tid] = tp1[b * NT + tid];
        sp2[tid] = tp2[b * NT + tid];
    }
    __syncthreads();

    const int lc = blockIdx.x * blockDim.x + tid;
    float lmain = 0.0f;

    if (lc < CELLS_PER_B) {
        const int a = lc / HW;
        const int rem = lc - a * HW;
        const int j = rem / NW;
        const int i = rem - j * NW;

        const float aw[3] = {1.28967f, 2.12714f, 3.27212f};
        const float ah[3] = {4.15014f, 5.09344f, 5.87423f};
        // ln(anchor) constants for tw/th
        const float law[3] = {0.25438842f, 0.75477730f, 1.18543813f};
        const float lah[3] = {1.42314173f, 1.62795138f, 1.77057764f};

        const float* base = out + (size_t)b * (NA * CH_PER_A * HW) + (size_t)(a * CH_PER_A) * HW + rem;
        float o0 = base[0];
        float o1 = base[HW];
        float o2 = base[2 * HW];
        float o3 = base[3 * HW];
        float o4 = base[4 * HW];

        float x = fsig(o0);
        float y = fsig(o1);
        float conf = fsig(o4);
        float pw = __expf(o2) * aw[a];
        float ph = __expf(o3) * ah[a];
        float px = x + (float)i;
        float py = y + (float)j;
        float px1 = px - 0.5f * pw, px2 = px + 0.5f * pw;
        float py1 = py - 0.5f * ph, py2 = py + 0.5f * ph;
        float parea06 = 0.6f * (pw * ph);

        bool sil = false;
        int tsel = -1;
        #pragma unroll 5
        for (int t = 0; t < NT; ++t) {
            float4 p1 = sp1[t];
            float4 p2 = sp2[t];
            float mx = fminf(p1.x, px1);
            float Mx = fmaxf(p1.y, px2);
            float my = fminf(p1.z, py1);
            float My = fmaxf(p1.w, py2);
            float cw = (p2.x + pw) - (Mx - mx);
            float ch = (p2.y + ph) - (My - my);
            float inter = fmaxf(cw, 0.0f) * fmaxf(ch, 0.0f);
            // iou>0.6  <=>  inter > 0.6*(areaA+areaP-inter)  <=>  1.6*inter > 0.6*(areaA+areaP)
            sil = sil || (1.6f * inter > (p2.z + parea06));
            if (__float_as_int(p2.w) == lc) tsel = t;   // last t wins (matches .at[].set)
        }

        if (tsel >= 0) {
            float4 g1 = sp1[tsel];
            float4 g2 = sp2[tsel];
            float gx = 0.5f * (g1.x + g1.y);
            float gy = 0.5f * (g1.z + g1.w);
            float tx = gx - (float)i;
            float ty = gy - (float)j;
            float tw = __logf(g2.x) - law[a];
            float th = __logf(g2.y) - lah[a];
            lmain += 0.5f * ((x - tx) * (x - tx) + (y - ty) * (y - ty) +
                             (o2 - tw) * (o2 - tw) + (o3 - th) * (o3 - th));
            // exact IoU for tconf
            float mx = fminf(g1.x, px1), Mx = fmaxf(g1.y, px2);
            float my = fminf(g1.z, py1), My = fmaxf(g1.w, py2);
            float cw = (g2.x + pw) - (Mx - mx);
            float ch = (g2.y + ph) - (My - my);
            float inter = fmaxf(cw, 0.0f) * fmaxf(ch, 0.0f);
            float uni = g2.x * g2.y + (pw * ph) - inter;
            float tconf = inter / uni;
            lmain += 2.5f * (conf - tconf) * (conf - tconf);

            int pos = atomicAdd(counter, 1);
            objlist[pos] = make_int2(b * CELLS_PER_B + lc, tsel);
        } else {
            lmain += sil ? 0.0f : 0.5f * conf * conf;
        }
    }

    // block reduction
    for (int off = 32; off > 0; off >>= 1)
        lmain += __shfl_down(lmain, off, 64);
    __shared__ float red[4];
    if ((tid & 63) == 0) red[tid >> 6] = lmain;
    __syncthreads();
    if (tid == 0)
        part[blockIdx.y * gridDim.x + blockIdx.x] = red[0] + red[1] + red[2] + red[3];
}

// ---------------------------------------------------------------------------
// Kernel 3: class loss, one block (128 thr) per object cell, lane-parallel
// over the 80 classes.
// ---------------------------------------------------------------------------
__global__ __launch_bounds__(128) void cls_kernel(const float* __restrict__ out,
                                                  const int2* __restrict__ objlist,
                                                  const int* __restrict__ counter,
                                                  const float* __restrict__ tcls,
                                                  const float* __restrict__ cwt,
                                                  float* __restrict__ clspart) {
    const int ob = blockIdx.x;
    if (ob >= counter[0]) return;
    int2 e = objlist[ob];
    const int cell = e.x, tsel = e.y;
    const int b = cell / CELLS_PER_B;
    const int r1 = cell - b * CELLS_PER_B;
    const int a = r1 / HW;
    const int rem = r1 - a * HW;

    const float* cb = out + (size_t)b * (NA * CH_PER_A * HW) + (size_t)(a * CH_PER_A + 5) * HW + rem;
    const float* tc = tcls + (size_t)(b * NT + tsel) * NC;

    const int tid = threadIdx.x;
    float l = 0.0f;
    if (tid < NC) {
        float p = fsig(cb[(size_t)tid * HW]);
        float w = cwt[tid];
        float l1 = sqrtf(1.0f - p + EPSF) * __logf(p + EPSF) * __expf(w);
        float l0 = sqrtf(p + EPSF) * __logf(1.0f - p + EPSF) * __expf(1.0f - w);
        float t = tc[tid];
        l = t * l1 + (1.0f - t) * l0;
    }
    for (int off = 32; off > 0; off >>= 1)
        l += __shfl_down(l, off, 64);
    __shared__ float r2[2];
    if ((tid & 63) == 0) r2[tid >> 6] = l;
    __syncthreads();
    if (tid == 0) clspart[ob] = r2[0] + r2[1];
}

// ---------------------------------------------------------------------------
// Kernel 4: finalize. Single block reduces partials.
// ---------------------------------------------------------------------------
__global__ __launch_bounds__(256) void finalize_kernel(const float* __restrict__ part,
                                                       const float* __restrict__ clspart,
                                                       const int* __restrict__ counter,
                                                       float* __restrict__ outp) {
    const int tid = threadIdx.x;
    const int cnt = counter[0];
    float m = 0.0f, c = 0.0f;
    for (int i = tid; i < NBLK_DENSE; i += 256) m += part[i];
    for (int i = tid; i < cnt; i += 256) c += clspart[i];
    for (int off = 32; off > 0; off >>= 1) {
        m += __shfl_down(m, off, 64);
        c += __shfl_down(c, off, 64);
    }
    __shared__ float rm[4], rc[4];
    if ((tid & 63) == 0) { rm[tid >> 6] = m; rc[tid >> 6] = c; }
    __syncthreads();
    if (tid == 0) {
        float ms = rm[0] + rm[1] + rm[2] + rm[3];
        float cs = rc[0] + rc[1] + rc[2] + rc[3];
        float nsel = fmaxf((float)cnt, 1.0f);
        outp[0] = ms - cs / nsel;
    }
}

extern "C" void kernel_launch(void* const* d_in, const int* in_sizes, int n_in,
                              void* d_out, int out_size, void* d_ws, size_t ws_size,
                              hipStream_t stream) {
    const float* output = (const float*)d_in[0];
    const float* tb     = (const float*)d_in[1];
    const float* tcls   = (const float*)d_in[2];
    const float* cwt    = (const float*)d_in[3];

    char* ws = (char*)d_ws;
    int*    counter = (int*)   (ws + WS_COUNTER);
    float4* tp1     = (float4*)(ws + WS_TP1);
    float4* tp2     = (float4*)(ws + WS_TP2);
    int2*   objlist = (int2*)  (ws + WS_OBJLIST);
    float*  part    = (float*) (ws + WS_PART);
    float*  clspart = (float*) (ws + WS_CLSPART);

    prep_kernel<<<dim3(7), 256, 0, stream>>>(tb, tp1, tp2, counter);
    main_kernel<<<dim3(NBLK_X, NB), 256, 0, stream>>>(output, tp1, tp2, part, objlist, counter);
    cls_kernel<<<dim3(MAXOBJ), 128, 0, stream>>>(output, objlist, counter, tcls, cwt, clspart);
    finalize_kernel<<<1, 256, 0, stream>>>(part, clspart, counter, (float*)d_out);
}